// Round 1
// baseline (845.300 us; speedup 1.0000x reference)
//
#include <hip/hip_runtime.h>
#include <hip/hip_bf16.h>
#include <math.h>

#define HID 32
#define POOLW 192  // 6 layers * 32

// ---------- graph prep ----------
__global__ void k_count(const int* __restrict__ dst, int* __restrict__ deg, int E) {
    int e = blockIdx.x * blockDim.x + threadIdx.x;
    if (e < E) atomicAdd(&deg[dst[e]], 1);
}

__global__ void k_dinv(const int* __restrict__ deg, float* __restrict__ dinv, int n) {
    int i = blockIdx.x * blockDim.x + threadIdx.x;
    if (i < n) dinv[i] = rsqrtf((float)(deg[i] + 1));  // +1 = self loop; deg>=1 always
}

// block scans 1024 elements (256 threads x 4)
__global__ void k_scan1(const int* __restrict__ deg, int* __restrict__ part,
                        int* __restrict__ bsum, int n) {
    __shared__ int sh[256];
    int t = threadIdx.x;
    int base = blockIdx.x * 1024 + t * 4;
    int v0 = (base + 0 < n) ? deg[base + 0] : 0;
    int v1 = (base + 1 < n) ? deg[base + 1] : 0;
    int v2 = (base + 2 < n) ? deg[base + 2] : 0;
    int v3 = (base + 3 < n) ? deg[base + 3] : 0;
    int s = v0 + v1 + v2 + v3;
    sh[t] = s;
    __syncthreads();
    for (int off = 1; off < 256; off <<= 1) {
        int xv = (t >= off) ? sh[t - off] : 0;
        __syncthreads();
        sh[t] += xv;
        __syncthreads();
    }
    int excl = sh[t] - s;
    if (t == 255) bsum[blockIdx.x] = sh[255];
    if (base + 0 < n) part[base + 0] = excl;
    if (base + 1 < n) part[base + 1] = excl + v0;
    if (base + 2 < n) part[base + 2] = excl + v0 + v1;
    if (base + 3 < n) part[base + 3] = excl + v0 + v1 + v2;
}

// exclusive scan of block sums (nb <= 256)
__global__ void k_scan2(int* __restrict__ bsum, int nb) {
    __shared__ int sh[256];
    int t = threadIdx.x;
    int v = (t < nb) ? bsum[t] : 0;
    sh[t] = v;
    __syncthreads();
    for (int off = 1; off < 256; off <<= 1) {
        int xv = (t >= off) ? sh[t - off] : 0;
        __syncthreads();
        sh[t] += xv;
        __syncthreads();
    }
    if (t < nb) bsum[t] = sh[t] - v;
}

__global__ void k_scan3(const int* __restrict__ part, const int* __restrict__ bsum,
                        int* __restrict__ offs, int* __restrict__ cursor, int n, int E) {
    int i = blockIdx.x * blockDim.x + threadIdx.x;
    if (i < n) {
        int v = part[i] + bsum[i >> 10];
        offs[i] = v;
        cursor[i] = v;
        if (i == 0) offs[n] = E;
    }
}

__global__ void k_fill(const int* __restrict__ src, const int* __restrict__ dst,
                       const float* __restrict__ dinv, int* __restrict__ cursor,
                       int* __restrict__ csr_src, float* __restrict__ csr_norm, int E) {
    int e = blockIdx.x * blockDim.x + threadIdx.x;
    if (e < E) {
        int s = src[e], d = dst[e];
        int pos = atomicAdd(&cursor[d], 1);
        csr_src[pos] = s;
        csr_norm[pos] = dinv[s] * dinv[d];
    }
}

// ---------- per-layer ----------
__global__ void k_transform0(const float* __restrict__ x, const float* __restrict__ W,
                             float* __restrict__ T, int n) {
    int idx = blockIdx.x * blockDim.x + threadIdx.x;
    if (idx < n * HID) {
        int i = idx >> 5, j = idx & 31;
        T[idx] = x[i] * W[j];
    }
}

__global__ __launch_bounds__(256) void k_transform32(const float* __restrict__ H,
                                                     const float* __restrict__ W,
                                                     float* __restrict__ T, int n) {
    __shared__ float wsh[HID * HID];
    __shared__ float hsh[256];
    int t = threadIdx.x;
    for (int k = t; k < HID * HID; k += 256) wsh[k] = W[k];
    int base = blockIdx.x * 256;
    int idx = base + t;
    hsh[t] = (idx < n * HID) ? H[idx] : 0.0f;
    __syncthreads();
    if (idx < n * HID) {
        int il = t >> 5, j = t & 31;
        float acc = 0.f;
#pragma unroll
        for (int k = 0; k < HID; ++k) acc += hsh[il * HID + k] * wsh[k * HID + j];
        T[idx] = acc;
    }
}

// gather + bias + relu + fused pooling (8 nodes per 256-thread block)
__global__ __launch_bounds__(256) void k_gather(
        const float* __restrict__ T, const int* __restrict__ offs,
        const int* __restrict__ csr_src, const float* __restrict__ csr_norm,
        const float* __restrict__ dinv, const float* __restrict__ bias,
        const int* __restrict__ batch, float* __restrict__ H,
        float* __restrict__ pooled, int n, int layer) {
    __shared__ float hred[8][HID];
    __shared__ int gid[8];
    int t = threadIdx.x;
    int il = t >> 5, j = t & 31;
    int node = blockIdx.x * 8 + il;
    bool valid = node < n;
    float h = 0.f;
    if (valid) {
        float di = dinv[node];
        float acc = di * di * T[node * HID + j];  // self loop
        int s0 = offs[node], s1 = offs[node + 1];
        for (int k = s0; k < s1; ++k) {
            int s = csr_src[k];
            acc += csr_norm[k] * T[s * HID + j];
        }
        h = fmaxf(acc + bias[j], 0.f);
        H[node * HID + j] = h;
    }
    hred[il][j] = valid ? h : 0.f;
    if (j == 0) gid[il] = valid ? batch[node] : -1;
    __syncthreads();
    if (t < HID) {
        float run = 0.f;
        int g = gid[0];
#pragma unroll
        for (int nn = 0; nn < 8; ++nn) {
            int gn = gid[nn];
            if (gn != g) {
                if (g >= 0) atomicAdd(&pooled[g * POOLW + layer * HID + t], run);
                run = 0.f;
                g = gn;
            }
            run += hred[nn][t];
        }
        if (g >= 0) atomicAdd(&pooled[g * POOLW + layer * HID + t], run);
    }
}

// ---------- head: fc1(192->128) + relu + fc2(128->2) + softmax ----------
__global__ __launch_bounds__(128) void k_mlp(const float* __restrict__ pooled,
                                             const float* __restrict__ fc1_w,
                                             const float* __restrict__ fc1_b,
                                             const float* __restrict__ fc2_w,
                                             const float* __restrict__ fc2_b,
                                             float* __restrict__ out, int G) {
    __shared__ float z[POOLW];
    __shared__ float w0s[2], w1s[2];
    int g = blockIdx.x;
    int t = threadIdx.x;
    for (int k = t; k < POOLW; k += 128) z[k] = pooled[g * POOLW + k];
    __syncthreads();
    float a = fc1_b[t];
    for (int k = 0; k < POOLW; ++k) a += z[k] * fc1_w[k * 128 + t];
    float z1 = fmaxf(a, 0.f);
    float p0 = z1 * fc2_w[t * 2 + 0];
    float p1 = z1 * fc2_w[t * 2 + 1];
    for (int off = 32; off >= 1; off >>= 1) {
        p0 += __shfl_down(p0, off, 64);
        p1 += __shfl_down(p1, off, 64);
    }
    if ((t & 63) == 0) { w0s[t >> 6] = p0; w1s[t >> 6] = p1; }
    __syncthreads();
    if (t == 0) {
        float o0 = w0s[0] + w0s[1] + fc2_b[0];
        float o1 = w1s[0] + w1s[1] + fc2_b[1];
        float m = fmaxf(o0, o1);
        float e0 = expf(o0 - m), e1 = expf(o1 - m);
        float s = e0 + e1;
        out[g * 2 + 0] = e0 / s;
        out[g * 2 + 1] = e1 / s;
    }
}

extern "C" void kernel_launch(void* const* d_in, const int* in_sizes, int n_in,
                              void* d_out, int out_size, void* d_ws, size_t ws_size,
                              hipStream_t stream) {
    const float* x     = (const float*)d_in[0];
    const int*   ei    = (const int*)d_in[1];
    const int*   batch = (const int*)d_in[2];
    const float* Ws[6] = {(const float*)d_in[3], (const float*)d_in[5],
                          (const float*)d_in[7], (const float*)d_in[9],
                          (const float*)d_in[11], (const float*)d_in[13]};
    const float* bs[6] = {(const float*)d_in[4], (const float*)d_in[6],
                          (const float*)d_in[8], (const float*)d_in[10],
                          (const float*)d_in[12], (const float*)d_in[14]};
    const float* fc1_w = (const float*)d_in[15];
    const float* fc1_b = (const float*)d_in[16];
    const float* fc2_w = (const float*)d_in[17];
    const float* fc2_b = (const float*)d_in[18];

    int n = in_sizes[0];       // 100000 (x is [n,1])
    int E = in_sizes[1] / 2;   // 1600000
    int G = out_size / 2;      // 256
    const int* src = ei;
    const int* dst = ei + E;

    char* p = (char*)d_ws;
    auto alloc = [&](size_t bytes) -> void* {
        void* r = (void*)p;
        p += (bytes + 255) / 256 * 256;
        return r;
    };
    int*   deg      = (int*)alloc((size_t)n * 4);
    int*   offs     = (int*)alloc((size_t)(n + 1) * 4);
    int*   cursor   = (int*)alloc((size_t)n * 4);
    int*   part     = (int*)alloc((size_t)n * 4);
    int*   bsum     = (int*)alloc(1024 * 4);
    float* dinv     = (float*)alloc((size_t)n * 4);
    int*   csr_src  = (int*)alloc((size_t)E * 4);
    float* csr_norm = (float*)alloc((size_t)E * 4);
    float* Hbuf     = (float*)alloc((size_t)n * HID * 4);
    float* Tbuf     = (float*)alloc((size_t)n * HID * 4);
    float* pooled   = (float*)alloc((size_t)G * POOLW * 4);

    hipMemsetAsync(deg, 0, (size_t)n * 4, stream);
    hipMemsetAsync(pooled, 0, (size_t)G * POOLW * 4, stream);

    int nb1024 = (n + 1023) / 1024;
    k_count<<<(E + 255) / 256, 256, 0, stream>>>(dst, deg, E);
    k_dinv<<<(n + 255) / 256, 256, 0, stream>>>(deg, dinv, n);
    k_scan1<<<nb1024, 256, 0, stream>>>(deg, part, bsum, n);
    k_scan2<<<1, 256, 0, stream>>>(bsum, nb1024);
    k_scan3<<<(n + 255) / 256, 256, 0, stream>>>(part, bsum, offs, cursor, n, E);
    k_fill<<<(E + 255) / 256, 256, 0, stream>>>(src, dst, dinv, cursor, csr_src, csr_norm, E);

    int nblk8 = (n + 7) / 8;
    for (int l = 0; l < 6; ++l) {
        if (l == 0)
            k_transform0<<<((size_t)n * HID + 255) / 256, 256, 0, stream>>>(x, Ws[0], Tbuf, n);
        else
            k_transform32<<<nblk8, 256, 0, stream>>>(Hbuf, Ws[l], Tbuf, n);
        k_gather<<<nblk8, 256, 0, stream>>>(Tbuf, offs, csr_src, csr_norm, dinv, bs[l],
                                            batch, Hbuf, pooled, n, l);
    }
    k_mlp<<<G, 128, 0, stream>>>(pooled, fc1_w, fc1_b, fc2_w, fc2_b, (float*)d_out, G);
}

// Round 2
// 546.317 us; speedup vs baseline: 1.5473x; 1.5473x over previous
//
#include <hip/hip_runtime.h>
#include <hip/hip_bf16.h>
#include <math.h>

#define HID 32
#define POOLW 192  // 6 layers * 32

// ---------- graph prep ----------
__global__ void k_count(const int* __restrict__ dst, int* __restrict__ deg, int E) {
    int e = blockIdx.x * blockDim.x + threadIdx.x;
    if (e < E) atomicAdd(&deg[dst[e]], 1);
}

__global__ void k_dinv(const int* __restrict__ deg, float* __restrict__ dinv, int n) {
    int i = blockIdx.x * blockDim.x + threadIdx.x;
    if (i < n) dinv[i] = rsqrtf((float)(deg[i] + 1));  // +1 = self loop
}

// block scans 1024 elements (256 threads x 4)
__global__ void k_scan1(const int* __restrict__ deg, int* __restrict__ part,
                        int* __restrict__ bsum, int n) {
    __shared__ int sh[256];
    int t = threadIdx.x;
    int base = blockIdx.x * 1024 + t * 4;
    int v0 = (base + 0 < n) ? deg[base + 0] : 0;
    int v1 = (base + 1 < n) ? deg[base + 1] : 0;
    int v2 = (base + 2 < n) ? deg[base + 2] : 0;
    int v3 = (base + 3 < n) ? deg[base + 3] : 0;
    int s = v0 + v1 + v2 + v3;
    sh[t] = s;
    __syncthreads();
    for (int off = 1; off < 256; off <<= 1) {
        int xv = (t >= off) ? sh[t - off] : 0;
        __syncthreads();
        sh[t] += xv;
        __syncthreads();
    }
    int excl = sh[t] - s;
    if (t == 255) bsum[blockIdx.x] = sh[255];
    if (base + 0 < n) part[base + 0] = excl;
    if (base + 1 < n) part[base + 1] = excl + v0;
    if (base + 2 < n) part[base + 2] = excl + v0 + v1;
    if (base + 3 < n) part[base + 3] = excl + v0 + v1 + v2;
}

__global__ void k_scan2(int* __restrict__ bsum, int nb) {
    __shared__ int sh[256];
    int t = threadIdx.x;
    int v = (t < nb) ? bsum[t] : 0;
    sh[t] = v;
    __syncthreads();
    for (int off = 1; off < 256; off <<= 1) {
        int xv = (t >= off) ? sh[t - off] : 0;
        __syncthreads();
        sh[t] += xv;
        __syncthreads();
    }
    if (t < nb) bsum[t] = sh[t] - v;
}

__global__ void k_scan3(const int* __restrict__ part, const int* __restrict__ bsum,
                        int* __restrict__ offs, int* __restrict__ cursor, int n, int E) {
    int i = blockIdx.x * blockDim.x + threadIdx.x;
    if (i < n) {
        int v = part[i] + bsum[i >> 10];
        offs[i] = v;
        cursor[i] = v;
        if (i == 0) offs[n] = E;
    }
}

__global__ void k_fill(const int* __restrict__ src, const int* __restrict__ dst,
                       int* __restrict__ cursor, int* __restrict__ csr_src, int E) {
    int e = blockIdx.x * blockDim.x + threadIdx.x;
    if (e < E) {
        int s = src[e], d = dst[e];
        int pos = atomicAdd(&cursor[d], 1);
        csr_src[pos] = s;
    }
}

// ---------- layer 0 transform: Tscaled = dinv * x * W1 (x is [n,1]) ----------
__global__ void k_transform0(const float* __restrict__ x, const float* __restrict__ dinv,
                             const float* __restrict__ W, float* __restrict__ T, int n) {
    int idx = blockIdx.x * blockDim.x + threadIdx.x;
    if (idx < n * HID) {
        int i = idx >> 5, j = idx & 31;
        T[idx] = dinv[i] * x[i] * W[j];
    }
}

// ---------- fused layer: gather + bias + relu + pooling + next-layer transform ----------
// 8 nodes per 256-thread block; 32 lanes per node (one per dim).
__global__ __launch_bounds__(256) void k_layer(
        const float* __restrict__ Tin, float* __restrict__ Tout,
        const int* __restrict__ offs, const int* __restrict__ csr_src,
        const float* __restrict__ dinv, const float* __restrict__ bias,
        const float* __restrict__ Wnext, const int* __restrict__ batch,
        float* __restrict__ pooled, int n, int layer, int last) {
    __shared__ float hred[8][HID];
    __shared__ float wsh[HID * HID];
    __shared__ int gid[8];
    int t = threadIdx.x;
    int il = t >> 5, j = t & 31;
    int node = blockIdx.x * 8 + il;
    bool valid = node < n;

    if (!last) {
        for (int k = t; k < HID * HID; k += 256) wsh[k] = Wnext[k];
    }

    float h = 0.f, di = 0.f;
    if (valid) {
        di = dinv[node];
        float a0 = Tin[node * HID + j];  // self loop term (Tscaled includes dinv[node])
        float a1 = 0.f, a2 = 0.f, a3 = 0.f;
        int s0 = offs[node], s1 = offs[node + 1];
        int k = s0;
        for (; k + 3 < s1; k += 4) {
            int sa = csr_src[k], sb = csr_src[k + 1];
            int sc = csr_src[k + 2], sd = csr_src[k + 3];
            a0 += Tin[sa * HID + j];
            a1 += Tin[sb * HID + j];
            a2 += Tin[sc * HID + j];
            a3 += Tin[sd * HID + j];
        }
        for (; k < s1; ++k) a0 += Tin[csr_src[k] * HID + j];
        float acc = (a0 + a1) + (a2 + a3);
        h = fmaxf(di * acc + bias[j], 0.f);
    }
    hred[il][j] = valid ? h : 0.f;
    if (j == 0) gid[il] = valid ? batch[node] : -1;
    __syncthreads();

    // pooling: segmented reduce over the block's 8 (sorted-batch) nodes
    if (t < HID) {
        float run = 0.f;
        int g = gid[0];
#pragma unroll
        for (int nn = 0; nn < 8; ++nn) {
            int gn = gid[nn];
            if (gn != g) {
                if (g >= 0) atomicAdd(&pooled[g * POOLW + layer * HID + t], run);
                run = 0.f;
                g = gn;
            }
            run += hred[nn][t];
        }
        if (g >= 0) atomicAdd(&pooled[g * POOLW + layer * HID + t], run);
    }

    // next-layer transform: Tout[node][j] = dinv[node] * sum_k h[node][k] * Wnext[k][j]
    if (!last && valid) {
        float accT = 0.f;
#pragma unroll
        for (int k = 0; k < HID; ++k) accT += hred[il][k] * wsh[k * HID + j];
        Tout[node * HID + j] = di * accT;
    }
}

// ---------- head: fc1(192->128) + relu + fc2(128->2) + softmax ----------
__global__ __launch_bounds__(128) void k_mlp(const float* __restrict__ pooled,
                                             const float* __restrict__ fc1_w,
                                             const float* __restrict__ fc1_b,
                                             const float* __restrict__ fc2_w,
                                             const float* __restrict__ fc2_b,
                                             float* __restrict__ out, int G) {
    __shared__ float z[POOLW];
    __shared__ float w0s[2], w1s[2];
    int g = blockIdx.x;
    int t = threadIdx.x;
    for (int k = t; k < POOLW; k += 128) z[k] = pooled[g * POOLW + k];
    __syncthreads();
    float a = fc1_b[t];
    for (int k = 0; k < POOLW; ++k) a += z[k] * fc1_w[k * 128 + t];
    float z1 = fmaxf(a, 0.f);
    float p0 = z1 * fc2_w[t * 2 + 0];
    float p1 = z1 * fc2_w[t * 2 + 1];
    for (int off = 32; off >= 1; off >>= 1) {
        p0 += __shfl_down(p0, off, 64);
        p1 += __shfl_down(p1, off, 64);
    }
    if ((t & 63) == 0) { w0s[t >> 6] = p0; w1s[t >> 6] = p1; }
    __syncthreads();
    if (t == 0) {
        float o0 = w0s[0] + w0s[1] + fc2_b[0];
        float o1 = w1s[0] + w1s[1] + fc2_b[1];
        float m = fmaxf(o0, o1);
        float e0 = expf(o0 - m), e1 = expf(o1 - m);
        float s = e0 + e1;
        out[g * 2 + 0] = e0 / s;
        out[g * 2 + 1] = e1 / s;
    }
}

extern "C" void kernel_launch(void* const* d_in, const int* in_sizes, int n_in,
                              void* d_out, int out_size, void* d_ws, size_t ws_size,
                              hipStream_t stream) {
    const float* x     = (const float*)d_in[0];
    const int*   ei    = (const int*)d_in[1];
    const int*   batch = (const int*)d_in[2];
    const float* Ws[6] = {(const float*)d_in[3], (const float*)d_in[5],
                          (const float*)d_in[7], (const float*)d_in[9],
                          (const float*)d_in[11], (const float*)d_in[13]};
    const float* bs[6] = {(const float*)d_in[4], (const float*)d_in[6],
                          (const float*)d_in[8], (const float*)d_in[10],
                          (const float*)d_in[12], (const float*)d_in[14]};
    const float* fc1_w = (const float*)d_in[15];
    const float* fc1_b = (const float*)d_in[16];
    const float* fc2_w = (const float*)d_in[17];
    const float* fc2_b = (const float*)d_in[18];

    int n = in_sizes[0];       // 100000
    int E = in_sizes[1] / 2;   // 1600000
    int G = out_size / 2;      // 256
    const int* src = ei;
    const int* dst = ei + E;

    char* p = (char*)d_ws;
    auto alloc = [&](size_t bytes) -> void* {
        void* r = (void*)p;
        p += (bytes + 255) / 256 * 256;
        return r;
    };
    int*   deg     = (int*)alloc((size_t)n * 4);
    int*   offs    = (int*)alloc((size_t)(n + 1) * 4);
    int*   cursor  = (int*)alloc((size_t)n * 4);
    int*   part    = (int*)alloc((size_t)n * 4);
    int*   bsum    = (int*)alloc(1024 * 4);
    float* dinv    = (float*)alloc((size_t)n * 4);
    int*   csr_src = (int*)alloc((size_t)E * 4);
    float* Ta      = (float*)alloc((size_t)n * HID * 4);
    float* Tb      = (float*)alloc((size_t)n * HID * 4);
    float* pooled  = (float*)alloc((size_t)G * POOLW * 4);

    hipMemsetAsync(deg, 0, (size_t)n * 4, stream);
    hipMemsetAsync(pooled, 0, (size_t)G * POOLW * 4, stream);

    int nb1024 = (n + 1023) / 1024;
    k_count<<<(E + 255) / 256, 256, 0, stream>>>(dst, deg, E);
    k_dinv<<<(n + 255) / 256, 256, 0, stream>>>(deg, dinv, n);
    k_scan1<<<nb1024, 256, 0, stream>>>(deg, part, bsum, n);
    k_scan2<<<1, 256, 0, stream>>>(bsum, nb1024);
    k_scan3<<<(n + 255) / 256, 256, 0, stream>>>(part, bsum, offs, cursor, n, E);
    k_fill<<<(E + 255) / 256, 256, 0, stream>>>(src, dst, cursor, csr_src, E);

    k_transform0<<<((size_t)n * HID + 255) / 256, 256, 0, stream>>>(x, dinv, Ws[0], Ta, n);

    int nblk8 = (n + 7) / 8;
    float* Tin = Ta;
    float* Tout = Tb;
    for (int l = 0; l < 6; ++l) {
        int last = (l == 5);
        k_layer<<<nblk8, 256, 0, stream>>>(Tin, Tout, offs, csr_src, dinv, bs[l],
                                           last ? nullptr : Ws[l + 1], batch,
                                           pooled, n, l, last);
        float* tmp = Tin; Tin = Tout; Tout = tmp;
    }
    k_mlp<<<G, 128, 0, stream>>>(pooled, fc1_w, fc1_b, fc2_w, fc2_b, (float*)d_out, G);
}